// Round 1
// baseline (96.149 us; speedup 1.0000x reference)
//
#include <hip/hip_runtime.h>
#include <hip/hip_bf16.h>

// Problem dims (fixed by reference)
#define B_   8
#define C_   256
#define N_   1024
#define HH_  8     // heads
#define DD_  32    // head dim

typedef __attribute__((ext_vector_type(8))) short bf16x8;
typedef __attribute__((ext_vector_type(4))) short bf16x4;
typedef __attribute__((ext_vector_type(4))) float f32x4;
typedef __attribute__((ext_vector_type(4))) float float4v;

static __device__ inline short f2bf(float f) {
    // round-to-nearest-even f32 -> bf16 (finite inputs only)
    unsigned u = __builtin_bit_cast(unsigned, f);
    unsigned lsb = (u >> 16) & 1u;
    u += 0x7fffu + lsb;
    return (short)(u >> 16);
}

// ---------------------------------------------------------------------------
// K0: transpose+cast  x[b][c][n] f32  ->  xT[b][n][c] bf16   (same for y)
// grid 256 blocks x 256 thr. Tile: 64 c x 256 n per block.
// ---------------------------------------------------------------------------
__global__ __launch_bounds__(256) void k_transpose(const float* __restrict__ x,
                                                   const float* __restrict__ y,
                                                   short* __restrict__ xT,
                                                   short* __restrict__ yT) {
    __shared__ short T[256][72];   // [n_local][c_local], padded stride
    int bx = blockIdx.x;
    int src = bx & 1;
    int b = (bx >> 1) & 7;
    int tile = bx >> 4;            // 0..15
    int c0 = (tile & 3) * 64;
    int n0 = (tile >> 2) * 256;
    const float* in = src ? y : x;
    short* out = src ? yT : xT;
    int t = threadIdx.x;
    int cl = t >> 2;               // 0..63
    int npart = (t & 3) * 64;
    const float* rowp = in + ((long)(b * C_ + c0 + cl) * N_) + n0 + npart;
#pragma unroll
    for (int u = 0; u < 16; ++u) {
        float4v v = *(const float4v*)(rowp + 4 * u);
        int nb = npart + 4 * u;
        T[nb + 0][cl] = f2bf(v[0]);
        T[nb + 1][cl] = f2bf(v[1]);
        T[nb + 2][cl] = f2bf(v[2]);
        T[nb + 3][cl] = f2bf(v[3]);
    }
    __syncthreads();
    short* orow = out + ((long)(b * N_ + n0 + t) * C_) + c0;
#pragma unroll
    for (int u = 0; u < 8; ++u)
        *(bf16x8*)(orow + 8 * u) = *(const bf16x8*)&T[t][8 * u];
}

// ---------------------------------------------------------------------------
// K1: projections.  out[b][n][co] = bias[co] + sum_ci A[b][n][ci] * W[co][ci]
// A = xT (p=0, ->q_nc) or yT (p=1, ->kv_nc), bf16 out.
// grid (16 tiles, 16 b*p), 256 thr (4 waves 2x2), tile 128(n) x 128(co), K=256.
// ---------------------------------------------------------------------------
__global__ __launch_bounds__(256) void k_proj(const short* __restrict__ xT,
                                              const short* __restrict__ yT,
                                              const float* __restrict__ Wq,
                                              const float* __restrict__ bq,
                                              const float* __restrict__ Wv,
                                              const float* __restrict__ bv,
                                              short* __restrict__ q_nc,
                                              short* __restrict__ kv_nc) {
    __shared__ short At[128][72];
    __shared__ short Bt[128][72];
    int by = blockIdx.y;
    int b = by >> 1, p = by & 1;
    const short* A = (p ? yT : xT) + (long)b * N_ * C_;
    const float* W = p ? Wv : Wq;
    const float* bias = p ? bv : bq;
    short* outp = (p ? kv_nc : q_nc) + (long)b * N_ * C_;
    int bx = blockIdx.x;
    int n0 = (bx >> 1) * 128;
    int co0 = (bx & 1) * 128;
    int t = threadIdx.x;
    int w = t >> 6, l = t & 63;
    int lr = l & 15, lg = l >> 4;
    int wr = (w >> 1) * 64, wc = (w & 1) * 64;
    f32x4 acc[4][4] = {};
    for (int kk = 0; kk < 256; kk += 64) {
        {   // stage A tile (bf16 passthrough)
            int r = t >> 1, off = (t & 1) * 32;
            const short* src = A + (long)(n0 + r) * C_ + kk + off;
            short* dst = &At[r][off];
#pragma unroll
            for (int u = 0; u < 4; ++u)
                *(bf16x8*)(dst + 8 * u) = *(const bf16x8*)(src + 8 * u);
        }
        {   // stage B tile (W f32 -> bf16)
            int r = t >> 1, off = (t & 1) * 32;
            const float* src = W + (long)(co0 + r) * C_ + kk + off;
            short tmp[32];
#pragma unroll
            for (int u = 0; u < 8; ++u) {
                float4v v = *(const float4v*)(src + 4 * u);
                tmp[4 * u + 0] = f2bf(v[0]); tmp[4 * u + 1] = f2bf(v[1]);
                tmp[4 * u + 2] = f2bf(v[2]); tmp[4 * u + 3] = f2bf(v[3]);
            }
            short* dst = &Bt[r][off];
#pragma unroll
            for (int u = 0; u < 4; ++u)
                *(bf16x8*)(dst + 8 * u) = *(const bf16x8*)&tmp[8 * u];
        }
        __syncthreads();
#pragma unroll
        for (int ks = 0; ks < 64; ks += 32) {
            bf16x8 af[4], bg[4];
#pragma unroll
            for (int fr = 0; fr < 4; ++fr)
                af[fr] = *(const bf16x8*)&At[wr + fr * 16 + lr][ks + lg * 8];
#pragma unroll
            for (int fc = 0; fc < 4; ++fc)
                bg[fc] = *(const bf16x8*)&Bt[wc + fc * 16 + lr][ks + lg * 8];
#pragma unroll
            for (int fr = 0; fr < 4; ++fr)
#pragma unroll
                for (int fc = 0; fc < 4; ++fc)
                    acc[fr][fc] = __builtin_amdgcn_mfma_f32_16x16x32_bf16(af[fr], bg[fc], acc[fr][fc], 0, 0, 0);
        }
        __syncthreads();
    }
#pragma unroll
    for (int fc = 0; fc < 4; ++fc) {
        int co = co0 + wc + fc * 16 + lr;
        float bb = bias[co];
#pragma unroll
        for (int fr = 0; fr < 4; ++fr)
#pragma unroll
            for (int jj = 0; jj < 4; ++jj) {
                int n = n0 + wr + fr * 16 + lg * 4 + jj;
                outp[(long)n * C_ + co] = f2bf(acc[fr][fc][jj] + bb);
            }
    }
}

// ---------------------------------------------------------------------------
// K2: attention.  out[b,h,j,dd] = (1/den_j) * sum_i exp(q_i . kv_j / 32) * kv[i][dd]
// Written directly in out2 layout: out2[b][(h*32+dd)*4 + (j>>8)][j&255] (bf16).
// grid 256 = (b*8+h)*4 + nhi; 4 waves, wave w owns j rows [nhi*256+w*64, +64).
// Score/PV via mfma 16x16x32; softmax WITHOUT max subtraction (scores ~ +-0.12).
// ---------------------------------------------------------------------------
__global__ __launch_bounds__(256) void k_attn(const short* __restrict__ q_nc,
                                              const short* __restrict__ kv_nc,
                                              short* __restrict__ out2) {
    __shared__ short MT[32][72];       // V^T chunk: [dd][i_local], shared
    __shared__ short Pl[4][64][72];    // per-wave P: [j_local][i_local]
    __shared__ float denL[4][64];
    int bx = blockIdx.x;
    int nhi = bx & 3;
    int bh = bx >> 2;
    int h = bh & 7, b = bh >> 3;
    int t = threadIdx.x, w = t >> 6, l = t & 63;
    int lr = l & 15, lg = l >> 4;
    int j0 = nhi * 256 + w * 64;
    const short* qb = q_nc + (long)b * N_ * C_;
    const short* kvb = kv_nc + (long)b * N_ * C_;
    bf16x8 mj[4];
#pragma unroll
    for (int fj = 0; fj < 4; ++fj)
        mj[fj] = *(const bf16x8*)&kvb[(long)(j0 + fj * 16 + lr) * C_ + h * 32 + lg * 8];
    f32x4 acc[4][2] = {};
    float den_p[4] = {0.f, 0.f, 0.f, 0.f};
    const f32x4 zero4 = {0.f, 0.f, 0.f, 0.f};
    for (int ic = 0; ic < 16; ++ic) {
        int i0 = ic * 64;
        __syncthreads();   // protect MT from previous iteration's readers
        {   // stage MT (V^T): wave w stages i rows [i0+w*16, +16)
            bf16x8 mv = *(const bf16x8*)&kvb[(long)(i0 + w * 16 + lr) * C_ + h * 32 + lg * 8];
#pragma unroll
            for (int e = 0; e < 8; ++e)
                MT[lg * 8 + e][w * 16 + lr] = mv[e];
        }
        // scores St[i][j] = q_i . kv_j ; P = exp(St/32) -> Pl[j][i] (bf16)
#pragma unroll
        for (int fi = 0; fi < 4; ++fi) {
            bf16x8 ka = *(const bf16x8*)&qb[(long)(i0 + fi * 16 + lr) * C_ + h * 32 + lg * 8];
#pragma unroll
            for (int fj = 0; fj < 4; ++fj) {
                f32x4 st = __builtin_amdgcn_mfma_f32_16x16x32_bf16(ka, mj[fj], zero4, 0, 0, 0);
                bf16x4 pk;
#pragma unroll
                for (int e = 0; e < 4; ++e) {
                    float pv = __expf(st[e] * 0.03125f);
                    den_p[fj] += pv;
                    pk[e] = f2bf(pv);
                }
                *(bf16x4*)&Pl[w][fj * 16 + lr][fi * 16 + lg * 4] = pk;
            }
        }
        __syncthreads();   // MT fully staged
        // PV: acc[j][dd] += P[j][i] * V[i][dd]
#pragma unroll
        for (int ks = 0; ks < 2; ++ks) {
            bf16x8 mb[2], pa[4];
#pragma unroll
            for (int fc = 0; fc < 2; ++fc)
                mb[fc] = *(const bf16x8*)&MT[fc * 16 + lr][ks * 32 + lg * 8];
#pragma unroll
            for (int fr = 0; fr < 4; ++fr) {
                pa[fr] = *(const bf16x8*)&Pl[w][fr * 16 + lr][ks * 32 + lg * 8];
#pragma unroll
                for (int fc = 0; fc < 2; ++fc)
                    acc[fr][fc] = __builtin_amdgcn_mfma_f32_16x16x32_bf16(pa[fr], mb[fc], acc[fr][fc], 0, 0, 0);
            }
        }
    }
    // denominator: reduce over lane groups (i spread over lg), then share per row j
#pragma unroll
    for (int fj = 0; fj < 4; ++fj) {
        float d = den_p[fj];
        d += __shfl_xor(d, 16, 64);
        d += __shfl_xor(d, 32, 64);
        if (lg == 0) denL[w][fj * 16 + lr] = d;
    }
    __syncthreads();
    // output: out2 row (h*32+dd)*4 + nhi, col j&255
#pragma unroll
    for (int fr = 0; fr < 4; ++fr) {
        float rr[4];
#pragma unroll
        for (int jj = 0; jj < 4; ++jj)
            rr[jj] = 1.0f / denL[w][fr * 16 + lg * 4 + jj];
#pragma unroll
        for (int fc = 0; fc < 2; ++fc) {
            int dd = fc * 16 + lr;
            bf16x4 ov;
#pragma unroll
            for (int jj = 0; jj < 4; ++jj)
                ov[jj] = f2bf(acc[fr][fc][jj] * rr[jj]);
            long orow = ((long)b * N_ + (h * 32 + dd) * 4 + nhi) * C_;
            *(bf16x4*)&out2[orow + w * 64 + fr * 16 + lg * 4] = ov;
        }
    }
}

// ---------------------------------------------------------------------------
// K3: final GEMM + LayerNorm.
// out[r][co] = LN_co( bf[co] + sum_c' out2[r][c'] * Wf[co][c'] ), f32 out.
// grid 128 (64 rows each), 4 waves: wave w -> cols [w*64, +64), K=256.
// ---------------------------------------------------------------------------
__global__ __launch_bounds__(256) void k_final(const short* __restrict__ out2,
                                               const float* __restrict__ Wf,
                                               const float* __restrict__ bf_,
                                               const float* __restrict__ gamma,
                                               const float* __restrict__ beta,
                                               float* __restrict__ out) {
    __shared__ short At[64][72];
    __shared__ short Bt[256][72];
    __shared__ float red[2][4][64];
    int bx = blockIdx.x;
    long row0 = (long)bx * 64;
    int t = threadIdx.x, w = t >> 6, l = t & 63;
    int lr = l & 15, lg = l >> 4;
    f32x4 acc[4][4] = {};
    for (int kk = 0; kk < 256; kk += 64) {
        {   // stage A: 64 x 64 bf16 from out2
            int r = t >> 2, off = (t & 3) * 16;
            const short* src = out2 + (row0 + r) * C_ + kk + off;
            *(bf16x8*)&At[r][off] = *(const bf16x8*)(src);
            *(bf16x8*)&At[r][off + 8] = *(const bf16x8*)(src + 8);
        }
        {   // stage B: 256 x 64 from Wf (f32 -> bf16)
            int r = t >> 1, off = (t & 1) * 32;
#pragma unroll
            for (int half = 0; half < 2; ++half) {
                int rr2 = r + half * 128;
                const float* src = Wf + (long)rr2 * C_ + kk + off;
                short tmp[32];
#pragma unroll
                for (int u = 0; u < 8; ++u) {
                    float4v v = *(const float4v*)(src + 4 * u);
                    tmp[4 * u + 0] = f2bf(v[0]); tmp[4 * u + 1] = f2bf(v[1]);
                    tmp[4 * u + 2] = f2bf(v[2]); tmp[4 * u + 3] = f2bf(v[3]);
                }
                short* dst = &Bt[rr2][off];
#pragma unroll
                for (int u = 0; u < 4; ++u)
                    *(bf16x8*)(dst + 8 * u) = *(const bf16x8*)&tmp[8 * u];
            }
        }
        __syncthreads();
#pragma unroll
        for (int ks = 0; ks < 64; ks += 32) {
            bf16x8 af[4], bg[4];
#pragma unroll
            for (int fr = 0; fr < 4; ++fr)
                af[fr] = *(const bf16x8*)&At[fr * 16 + lr][ks + lg * 8];
#pragma unroll
            for (int fc = 0; fc < 4; ++fc)
                bg[fc] = *(const bf16x8*)&Bt[w * 64 + fc * 16 + lr][ks + lg * 8];
#pragma unroll
            for (int fr = 0; fr < 4; ++fr)
#pragma unroll
                for (int fc = 0; fc < 4; ++fc)
                    acc[fr][fc] = __builtin_amdgcn_mfma_f32_16x16x32_bf16(af[fr], bg[fc], acc[fr][fc], 0, 0, 0);
        }
        __syncthreads();
    }
    // bias, then per-row mean/var (cols split across 4 waves)
    float gm[4], bt[4];
#pragma unroll
    for (int fc = 0; fc < 4; ++fc) {
        int co = w * 64 + fc * 16 + lr;
        float bb = bf_[co];
        gm[fc] = gamma[co];
        bt[fc] = beta[co];
#pragma unroll
        for (int fr = 0; fr < 4; ++fr)
#pragma unroll
            for (int jj = 0; jj < 4; ++jj)
                acc[fr][fc][jj] += bb;
    }
#pragma unroll
    for (int fr = 0; fr < 4; ++fr)
#pragma unroll
        for (int jj = 0; jj < 4; ++jj) {
            float s = 0.f, sq = 0.f;
#pragma unroll
            for (int fc = 0; fc < 4; ++fc) {
                float v = acc[fr][fc][jj];
                s += v; sq += v * v;
            }
#pragma unroll
            for (int m = 1; m < 16; m <<= 1) {
                s += __shfl_xor(s, m, 64);
                sq += __shfl_xor(sq, m, 64);
            }
            if (lr == 0) {
                red[0][w][fr * 16 + lg * 4 + jj] = s;
                red[1][w][fr * 16 + lg * 4 + jj] = sq;
            }
        }
    __syncthreads();
#pragma unroll
    for (int fr = 0; fr < 4; ++fr)
#pragma unroll
        for (int jj = 0; jj < 4; ++jj) {
            int r = fr * 16 + lg * 4 + jj;
            float s = red[0][0][r] + red[0][1][r] + red[0][2][r] + red[0][3][r];
            float sq = red[1][0][r] + red[1][1][r] + red[1][2][r] + red[1][3][r];
            float mu = s * (1.0f / 256.0f);
            float var = sq * (1.0f / 256.0f) - mu * mu;
            float rs = rsqrtf(var + 1e-5f);
#pragma unroll
            for (int fc = 0; fc < 4; ++fc)
                out[(row0 + r) * C_ + w * 64 + fc * 16 + lr] =
                    (acc[fr][fc][jj] - mu) * rs * gm[fc] + bt[fc];
        }
}

// ---------------------------------------------------------------------------
extern "C" void kernel_launch(void* const* d_in, const int* in_sizes, int n_in,
                              void* d_out, int out_size, void* d_ws, size_t ws_size,
                              hipStream_t stream) {
    (void)in_sizes; (void)n_in; (void)out_size; (void)ws_size;
    const float* x     = (const float*)d_in[0];
    const float* y     = (const float*)d_in[1];
    const float* Wq    = (const float*)d_in[2];
    const float* bq    = (const float*)d_in[3];
    const float* Wv    = (const float*)d_in[4];
    const float* bv    = (const float*)d_in[5];
    const float* Wf    = (const float*)d_in[6];
    const float* bf    = (const float*)d_in[7];
    const float* gamma = (const float*)d_in[8];
    const float* beta  = (const float*)d_in[9];
    float* out = (float*)d_out;

    // workspace: 5 bf16 buffers of 8*1024*256 = 2M elems (4 MB) each = 20 MB
    const long SZ = (long)B_ * N_ * C_;
    short* xT    = (short*)d_ws;
    short* yT    = xT + SZ;
    short* q_nc  = yT + SZ;
    short* kv_nc = q_nc + SZ;
    short* out2  = kv_nc + SZ;

    k_transpose<<<256, 256, 0, stream>>>(x, y, xT, yT);
    k_proj<<<dim3(16, 16), 256, 0, stream>>>(xT, yT, Wq, bq, Wv, bv, q_nc, kv_nc);
    k_attn<<<256, 256, 0, stream>>>(q_nc, kv_nc, out2);
    k_final<<<128, 256, 0, stream>>>(out2, Wf, bf, gamma, beta, out);
}